// Round 3
// baseline (23645.064 us; speedup 1.0000x reference)
//
#include <hip/hip_runtime.h>
#include <math.h>

typedef unsigned short u16;
typedef unsigned int u32;
typedef unsigned long long u64;

#define NSYN 37
#define NB   2048
#define KS   296
#define KREP 305          // replica stride (floats): bank shifts {0,17,2,19} mod 32
#define TSTEPS 2000
#define SFRAMES 200
#define HID 256
#define OUTC 39
#define KW  (4*KREP)      // 1220 floats of LDS

// ws layout (byte offsets, 64B aligned)
#define WS_WIN    0u          // float [2][37][2048]   raw (natural synapse order)
#define WS_IDXIN  606208u     // u16   [2][37][2048]   raw synapse indices
#define WS_WSC    909312u     // float [2][37][2048]   scheduled weights
#define WS_OFFSC  1515520u    // u16   [2][37][2048]   scheduled LDS byte offsets
#define WS_BETA   1818624u    // float [2][2048]
#define WS_CB     1835008u    // float [2][2048]
#define WS_ALPHA  1851392u    // float [2][256]
#define WS_FRAMES 1853440u    // float [2][32][200][256]
#define WS_Y      14960640u   // float [200][32][39]

// ---------------------------------------------------------------- setup ----
__global__ void build_sparse(
    const float* __restrict__ w_fw, const float* __restrict__ b_fw,
    const float* __restrict__ tau_n_fw, const float* __restrict__ mask_fw,
    const float* __restrict__ w_bw, const float* __restrict__ b_bw,
    const float* __restrict__ tau_n_bw, const float* __restrict__ mask_bw,
    const float* __restrict__ tau_m_fw, const float* __restrict__ tau_m_bw,
    float* __restrict__ W, u16* __restrict__ IDX, float* __restrict__ BETA,
    float* __restrict__ CB, float* __restrict__ ALPHA)
{
  const int rid = blockIdx.x * 256 + threadIdx.x;
  if (rid < 2 * NB) {
    const int dir = rid >> 11, r = rid & (NB - 1);
    const float* w  = dir ? w_bw : w_fw;
    const float* mk = dir ? mask_bw : mask_fw;
    const float* bb = dir ? b_bw : b_fw;
    const float* tn = dir ? tau_n_bw : tau_n_fw;
    int cnt = 0;
    for (int j = 0; j < KS && cnt < NSYN; ++j) {
      const float m = mk[(size_t)r * KS + j];
      if (m != 0.0f) {
        W[((size_t)dir * NSYN + cnt) * NB + r]   = w[(size_t)r * KS + j];
        IDX[((size_t)dir * NSYN + cnt) * NB + r] = (u16)j;
        ++cnt;
      }
    }
    for (; cnt < NSYN; ++cnt) {
      W[((size_t)dir * NSYN + cnt) * NB + r]   = 0.0f;
      IDX[((size_t)dir * NSYN + cnt) * NB + r] = (u16)(KS - 1);
    }
    const float bet = 1.0f / (1.0f + expf(-tn[r]));
    BETA[dir * NB + r] = bet;
    CB[dir * NB + r]   = (1.0f - bet) * bb[r];
  }
  if (rid < 2 * HID) {
    const int dir = rid >> 8, h = rid & (HID - 1);
    const float* tm = dir ? tau_m_bw : tau_m_fw;
    ALPHA[rid] = 1.0f / (1.0f + expf(-tm[h]));
  }
}

// Per-(dir,wave,component) greedy slot scheduler: each recurrent-kernel lane may
// process its 37 synapses in any order and read any of 4 LDS replicas (bank
// shifts {0,17,2,19}). For each instruction slot, pick (item, replica) keeping
// <=2 lanes per bank (2-way LDS conflicts are free on CDNA4).
__global__ void schedule_lanes(const float* __restrict__ W_in,
                               const u16* __restrict__ IDX_in,
                               float* __restrict__ W_sc,
                               u16* __restrict__ OFF_sc)
{
  __shared__ unsigned char cnt[32 * NSYN * 32];   // [local prob][slot][bank]
  const int pl = threadIdx.x;                     // 0..31
  const int p  = blockIdx.x * 32 + pl;            // 0..63 problems
  const int dir = p >> 5, wv = (p >> 2) & 7, comp = p & 3;
  unsigned char* C = &cnt[pl * (NSYN * 32)];
  for (int i = 0; i < NSYN * 32; ++i) C[i] = 0;
  const int SH[4] = {0, 17, 2, 19};
  const size_t dbase = (size_t)dir * (NSYN * NB);
  for (int l = 0; l < 64; ++l) {
    const int row = (wv * 64 + l) * 4 + comp;
    u16 idxl[NSYN];
    for (int i = 0; i < NSYN; ++i) idxl[i] = IDX_in[dbase + (size_t)i * NB + row];
    u64 used = 0;
    for (int s = 0; s < NSYN; ++s) {
      int besti = -1, bestc = 0, bestcost = 1 << 30;
      int seen = 0;
      for (int i = 0; i < NSYN && seen < 12; ++i) {
        if (used & (1ull << i)) continue;
        ++seen;
        for (int c = 0; c < 4; ++c) {
          const int bank = (idxl[i] + SH[c]) & 31;
          const int cost = C[s * 32 + bank];
          if (cost < bestcost) { bestcost = cost; besti = i; bestc = c; }
        }
        if (bestcost <= 1) break;     // <=2 lanes/bank after us: free
      }
      used |= (1ull << besti);
      const int bank = (idxl[besti] + SH[bestc]) & 31;
      C[s * 32 + bank]++;
      OFF_sc[dbase + (size_t)s * NB + row] =
          (u16)(((u32)bestc * KREP + (u32)idxl[besti]) * 4u);
      W_sc[dbase + (size_t)s * NB + row] = W_in[dbase + (size_t)besti * NB + row];
    }
  }
}

// ------------------------------------------------------- recurrent core ----
// grid = 64 (dir*32 + batch), block = 512, thread t owns branches 4t..4t+3.
// amdgpu_waves_per_eu(2,2): pin occupancy to 2 waves/EU so the allocator may
// use up to 256 VGPRs -> 222-reg weight/offset set stays register-resident.
__global__ __launch_bounds__(512)
__attribute__((amdgpu_waves_per_eu(2, 2)))
void snn_recurrent(
    const float* __restrict__ x, const float* __restrict__ W,
    const u16* __restrict__ OFF, const float* __restrict__ BETA,
    const float* __restrict__ CB, const float* __restrict__ ALPHA,
    float* __restrict__ FRAMES)
{
  const int wg  = blockIdx.x;
  const int dir = wg >> 5, b = wg & 31;
  const int tid = threadIdx.x;
  const int r0  = tid * 4;

  __shared__ float ksh[KW];
  for (int i = tid; i < KW; i += 512) ksh[i] = 0.0f;

  float wv0[NSYN], wv1[NSYN], wv2[NSYN], wv3[NSYN];
  u32 op0[NSYN], op1[NSYN];
  const float* Wd = W + (size_t)dir * (NSYN * NB);
  const u16*  Od  = OFF + (size_t)dir * (NSYN * NB);
#pragma unroll
  for (int s = 0; s < NSYN; ++s) {
    const float4 w4 = *reinterpret_cast<const float4*>(Wd + s * NB + r0);
    wv0[s] = w4.x; wv1[s] = w4.y; wv2[s] = w4.z; wv3[s] = w4.w;
    const uint2 i4 = *reinterpret_cast<const uint2*>(Od + s * NB + r0);
    op0[s] = i4.x;          // two u16 LDS byte-offsets packed
    op1[s] = i4.y;
  }
  const float4 be = *reinterpret_cast<const float4*>(BETA + dir * NB + r0);
  const float4 cb = *reinterpret_cast<const float4*>(CB + dir * NB + r0);
  const float alpha = ALPHA[dir * HID + (tid >> 1)];

  const float* xb = x + (size_t)b * (SFRAMES * 39);
  float* frow = FRAMES + ((size_t)(dir * 32 + b)) * (SFRAMES * HID) + (tid >> 1);

  float d0 = 0.f, d1 = 0.f, d2 = 0.f, d3 = 0.f;
  float mem = 0.f, spk = 0.f, facc = 0.f;

  // frame 0 into all replicas (both directions read frame 0 at step 0)
  if (tid < 39) {
    const float xv = xb[tid];
#pragma unroll
    for (int c = 0; c < 4; ++c) ksh[c * KREP + tid] = xv;
  }
  __syncthreads();

  const char* kb = reinterpret_cast<const char*>(&ksh[0]);

#pragma unroll 1
  for (int st = 0; st < TSTEPS; ++st) {
    // sparse gather-dot: 4 branches x 37 synapses, slot-scheduled replicas
    float a0 = 0.f, a1 = 0.f, a2 = 0.f, a3 = 0.f;
#pragma unroll
    for (int s = 0; s < NSYN; ++s) {
      const u32 p0 = op0[s], p1 = op1[s];
      a0 += wv0[s] * *reinterpret_cast<const float*>(kb + (p0 & 0xFFFFu));
      a1 += wv1[s] * *reinterpret_cast<const float*>(kb + (p0 >> 16));
      a2 += wv2[s] * *reinterpret_cast<const float*>(kb + (p1 & 0xFFFFu));
      a3 += wv3[s] * *reinterpret_cast<const float*>(kb + (p1 >> 16));
    }
    __syncthreads();   // all reads of k done before anyone rewrites it

    d0 = be.x * (d0 - a0) + (a0 + cb.x);
    d1 = be.y * (d1 - a1) + (a1 + cb.y);
    d2 = be.z * (d2 - a2) + (a2 + cb.z);
    d3 = be.w * (d3 - a3) + (a3 + cb.w);
    const float ps = d0 + d1 + d2 + d3;
    const float dsum = ps + __shfl_xor(ps, 1);
    mem = alpha * (mem - dsum) + dsum - spk;
    spk = (mem > 1.0f) ? 1.0f : 0.0f;
    facc += spk;

    // publish spike to 2 of the 4 replicas (pair thread covers the others)
    {
      const int n  = tid >> 1;
      const int c0 = (tid & 1) * 2;
      float* pp = &ksh[c0 * KREP + 39 + n];
      pp[0]    = spk;
      pp[KREP] = spk;
    }

    // frame-mean write at the end of every 10 steps
    if ((st % 10) == 9) {
      if ((tid & 1) == 0) frow[(st / 10) * HID] = facc * 0.1f;
      facc = 0.f;
    }
    // x-frame refresh: fw frames change at l%10==0 (load at end of st%10==9);
    // bw frames change at l%10==1 (load at end of st%10==0)
    const bool xload = (dir == 0) ? ((st % 10) == 9) : ((st % 10) == 0);
    if (xload && tid < 39) {
      int nf = (dir == 0) ? ((st + 10) / 10) : ((200 - (st + 10) / 10) % 200);
      if (nf > 199) nf = 0;   // fw st=1999: value never consumed
      const float xv = xb[nf * 39 + tid];
#pragma unroll
      for (int c = 0; c < 4; ++c) ksh[c * KREP + tid] = xv;
    }
    __syncthreads();   // k ready for next step
  }
}

// ------------------------------------------------------------- readout ----
__global__ void ro_matmul(const float* __restrict__ FRAMES,
                          const float* __restrict__ w_ro,
                          const float* __restrict__ b_ro,
                          float* __restrict__ Y)
{
  const int bid = blockIdx.x;          // s*32 + b
  const int s = bid >> 5, b = bid & 31;
  __shared__ float row[512];
  const float* Ff = FRAMES + ((size_t)(0 * 32 + b) * SFRAMES + s) * HID;
  const float* Fb = FRAMES + ((size_t)(1 * 32 + b) * SFRAMES + (SFRAMES - 1 - s)) * HID;
  for (int i = threadIdx.x; i < HID; i += 64) {
    row[i] = Ff[i];
    row[HID + i] = Fb[i];
  }
  __syncthreads();
  const int o = threadIdx.x;
  if (o < OUTC) {
    float acc = b_ro[o];
    const float* wr = w_ro + (size_t)o * 512;
#pragma unroll 8
    for (int k = 0; k < 512; ++k) acc += row[k] * wr[k];
    Y[(size_t)bid * OUTC + o] = acc;
  }
}

__global__ void ro_scan(const float* __restrict__ Y,
                        const float* __restrict__ tau_ro,
                        const int* __restrict__ labels,
                        float* __restrict__ out)
{
  const int b = blockIdx.x;            // 32 blocks
  const int o = threadIdx.x;           // 64 threads
  __shared__ float mems[SFRAMES * 40];
  if (o < OUTC) {
    const float ar = 1.0f / (1.0f + expf(-tau_ro[o]));
    const float om = 1.0f - ar;
    float m = 0.0f;
    for (int s = 0; s < SFRAMES; ++s) {
      m = ar * m + om * Y[((size_t)s * 32 + b) * OUTC + o];
      mems[s * 40 + o] = m;
    }
  }
  __syncthreads();
  for (int s = threadIdx.x; s < SFRAMES; s += 64) {
    float mx = -1e30f;
    for (int j = 0; j < OUTC; ++j) mx = fmaxf(mx, mems[s * 40 + j]);
    float se = 0.0f;
    for (int j = 0; j < OUTC; ++j) se += expf(mems[s * 40 + j] - mx);
    const float lse = logf(se);
    float* op = out + ((size_t)s * 32 + b) * OUTC;
    for (int j = 0; j < OUTC; ++j) op[j] = mems[s * 40 + j] - mx - lse;
    const int lab = labels[b * SFRAMES + s];
    const float nll = -(mems[s * 40 + lab] - mx - lse);
    atomicAdd(out + SFRAMES * 32 * OUTC, nll * (1.0f / 32.0f));
  }
}

// -------------------------------------------------------------- launch ----
extern "C" void kernel_launch(void* const* d_in, const int* in_sizes, int n_in,
                              void* d_out, int out_size, void* d_ws, size_t ws_size,
                              hipStream_t stream)
{
  const float* x        = (const float*)d_in[0];
  const int*   labels   = (const int*)d_in[1];
  const float* w_fw     = (const float*)d_in[2];
  const float* b_fw     = (const float*)d_in[3];
  const float* tau_m_fw = (const float*)d_in[4];
  const float* tau_n_fw = (const float*)d_in[5];
  const float* mask_fw  = (const float*)d_in[6];
  const float* w_bw     = (const float*)d_in[7];
  const float* b_bw     = (const float*)d_in[8];
  const float* tau_m_bw = (const float*)d_in[9];
  const float* tau_n_bw = (const float*)d_in[10];
  const float* mask_bw  = (const float*)d_in[11];
  const float* w_ro     = (const float*)d_in[12];
  const float* b_ro     = (const float*)d_in[13];
  const float* tau_m_ro = (const float*)d_in[14];
  float* out = (float*)d_out;

  char* ws = (char*)d_ws;
  float* W_in   = (float*)(ws + WS_WIN);
  u16*   IDX_in = (u16*)(ws + WS_IDXIN);
  float* W_sc   = (float*)(ws + WS_WSC);
  u16*   OFF_sc = (u16*)(ws + WS_OFFSC);
  float* BETA   = (float*)(ws + WS_BETA);
  float* CB     = (float*)(ws + WS_CB);
  float* ALPHA  = (float*)(ws + WS_ALPHA);
  float* FRAMES = (float*)(ws + WS_FRAMES);
  float* Y      = (float*)(ws + WS_Y);

  hipMemsetAsync(out + SFRAMES * 32 * OUTC, 0, sizeof(float), stream);

  build_sparse<<<16, 256, 0, stream>>>(w_fw, b_fw, tau_n_fw, mask_fw,
                                       w_bw, b_bw, tau_n_bw, mask_bw,
                                       tau_m_fw, tau_m_bw,
                                       W_in, IDX_in, BETA, CB, ALPHA);
  schedule_lanes<<<2, 32, 0, stream>>>(W_in, IDX_in, W_sc, OFF_sc);
  snn_recurrent<<<64, 512, 0, stream>>>(x, W_sc, OFF_sc, BETA, CB, ALPHA, FRAMES);
  ro_matmul<<<SFRAMES * 32, 64, 0, stream>>>(FRAMES, w_ro, b_ro, Y);
  ro_scan<<<32, 64, 0, stream>>>(Y, tau_m_ro, labels, out);
}

// Round 4
// 2450.475 us; speedup vs baseline: 9.6492x; 9.6492x over previous
//
#include <hip/hip_runtime.h>
#include <math.h>

typedef unsigned short u16;
typedef unsigned int u32;
typedef unsigned long long u64;

#define NSYN 37
#define NB   2048
#define KS   296
#define TSTEPS 2000
#define SFRAMES 200
#define HID 256
#define OUTC 39

// ws layout (byte offsets, 64B aligned)
#define WS_W      0u          // float [2][37][2048]
#define WS_OFF    606208u     // u16   [2][37][2048]  LDS byte offsets (idx*4)
#define WS_BETA   909312u     // float [2][2048]
#define WS_CB     925696u     // float [2][2048]
#define WS_ALPHA  942080u     // float [2][256]
#define WS_FRAMES 944128u     // float [2][32][200][256]
#define WS_Y      14051328u   // float [200][32][39]

// ---------------------------------------------------------------- setup ----
__global__ void build_sparse(
    const float* __restrict__ w_fw, const float* __restrict__ b_fw,
    const float* __restrict__ tau_n_fw, const float* __restrict__ mask_fw,
    const float* __restrict__ w_bw, const float* __restrict__ b_bw,
    const float* __restrict__ tau_n_bw, const float* __restrict__ mask_bw,
    const float* __restrict__ tau_m_fw, const float* __restrict__ tau_m_bw,
    float* __restrict__ W, u16* __restrict__ OFF, float* __restrict__ BETA,
    float* __restrict__ CB, float* __restrict__ ALPHA)
{
  const int rid = blockIdx.x * 256 + threadIdx.x;
  if (rid < 2 * NB) {
    const int dir = rid >> 11, r = rid & (NB - 1);
    const float* w  = dir ? w_bw : w_fw;
    const float* mk = dir ? mask_bw : mask_fw;
    const float* bb = dir ? b_bw : b_fw;
    const float* tn = dir ? tau_n_bw : tau_n_fw;
    int cnt = 0;
    for (int j = 0; j < KS && cnt < NSYN; ++j) {
      const float m = mk[(size_t)r * KS + j];
      if (m != 0.0f) {
        W[((size_t)dir * NSYN + cnt) * NB + r]   = w[(size_t)r * KS + j];
        OFF[((size_t)dir * NSYN + cnt) * NB + r] = (u16)(j * 4);
        ++cnt;
      }
    }
    for (; cnt < NSYN; ++cnt) {
      W[((size_t)dir * NSYN + cnt) * NB + r]   = 0.0f;
      OFF[((size_t)dir * NSYN + cnt) * NB + r] = (u16)((KS - 1) * 4);
    }
    const float bet = 1.0f / (1.0f + expf(-tn[r]));
    BETA[dir * NB + r] = bet;
    CB[dir * NB + r]   = (1.0f - bet) * bb[r];
  }
  if (rid < 2 * HID) {
    const int dir = rid >> 8, h = rid & (HID - 1);
    const float* tm = dir ? tau_m_bw : tau_m_fw;
    ALPHA[rid] = 1.0f / (1.0f + expf(-tm[h]));
  }
}

// ------------------------------------------------------- recurrent core ----
// grid = 64 (dir*32 + batch), block = 1024, thread t owns branches 2t, 2t+1.
// 74 weight regs + 37 packed-offset regs fit the 128-VGPR cap (16 waves/block
// -> 4 waves/EU). Fast path: gather result cached per frame; recomputed only
// when the input frame changes or any spike is live (block-wide LDS flag,
// 3-slot rotation so reset/OR/read are in separate barrier epochs).
__global__ __launch_bounds__(1024) void snn_recurrent(
    const float* __restrict__ x, const float* __restrict__ W,
    const u16* __restrict__ OFF, const float* __restrict__ BETA,
    const float* __restrict__ CB, const float* __restrict__ ALPHA,
    float* __restrict__ FRAMES)
{
  const int wg  = blockIdx.x;
  const int dir = wg >> 5, b = wg & 31;
  const int tid = threadIdx.x;
  const int r0  = tid * 2;

  __shared__ float ksh[KS];
  __shared__ u32 sflag[3];
  for (int i = tid; i < KS; i += 1024) ksh[i] = 0.0f;
  if (tid < 3) sflag[tid] = 0u;

  float wv0[NSYN], wv1[NSYN];
  u32 op[NSYN];
  const float* Wd = W + (size_t)dir * (NSYN * NB);
  const u16*  Od  = OFF + (size_t)dir * (NSYN * NB);
#pragma unroll
  for (int s = 0; s < NSYN; ++s) {
    const float2 w2 = *reinterpret_cast<const float2*>(Wd + s * NB + r0);
    wv0[s] = w2.x; wv1[s] = w2.y;
    op[s] = *reinterpret_cast<const u32*>(Od + s * NB + r0);
  }
  const float be0 = BETA[dir * NB + r0], be1 = BETA[dir * NB + r0 + 1];
  const float cb0 = CB[dir * NB + r0],  cb1 = CB[dir * NB + r0 + 1];
  const float alpha = ALPHA[dir * HID + (tid >> 2)];

  const float* xb = x + (size_t)b * (SFRAMES * 39);
  float* frow = FRAMES + ((size_t)(dir * 32 + b)) * (SFRAMES * HID) + (tid >> 2);

  float d0 = 0.f, d1 = 0.f, lin0 = 0.f, lin1 = 0.f;
  float mem = 0.f, spk = 0.f, facc = 0.f;
  u32 F = 0;
  bool stale = true;

  if (tid < 39) ksh[tid] = xb[tid];   // frame 0 (both dirs read frame 0 at step 0)
  __syncthreads();

  const char* kb = reinterpret_cast<const char*>(&ksh[0]);

#pragma unroll 1
  for (int st = 0; st < TSTEPS; ++st) {
    if (tid == 0) sflag[(st + 1) % 3] = 0u;   // reset 2 epochs before its ORs

    const int m10 = st - (st / 10) * 10;
    // x-frame refresh: fw frames change at l%10==0 (load at end of st%10==9);
    // bw frames change at l%10==1 (load at end of st%10==0)
    const bool xload = (dir == 0) ? (m10 == 9) : (m10 == 0);
    float xv = 0.f;
    if (xload && tid < 39) {
      int nf = (dir == 0) ? ((st + 10) / 10) : ((200 - (st + 10) / 10) % 200);
      if (nf > 199) nf = 0;   // fw st=1999: value never consumed
      xv = xb[nf * 39 + tid];
    }

    const bool newfr = (dir == 0) ? (m10 == 0) : (m10 == 1 || st == 0);
    if (newfr) stale = true;

    float acc0, acc1;
    if (F || stale) {                    // uniform across block
      float a0 = 0.f, a1 = 0.f;
#pragma unroll
      for (int s = 0; s < NSYN; ++s) {
        const u32 p = op[s];
        a0 += wv0[s] * *reinterpret_cast<const float*>(kb + (p & 0xFFFFu));
        a1 += wv1[s] * *reinterpret_cast<const float*>(kb + (p >> 16));
      }
      acc0 = a0; acc1 = a1;
      if (!F) { lin0 = a0; lin1 = a1; stale = false; }  // spikes zero: cacheable
      __syncthreads();                   // k reads done before anyone rewrites
    } else {
      acc0 = lin0; acc1 = lin1;          // bitwise equal to gather w/ zero spikes
    }

    d0 = be0 * (d0 - acc0) + (acc0 + cb0);
    d1 = be1 * (d1 - acc1) + (acc1 + cb1);
    const float ps = d0 + d1;
    const float s1 = ps + __shfl_xor(ps, 1);
    const float dsum = s1 + __shfl_xor(s1, 2);
    mem = alpha * (mem - dsum) + dsum - spk;
    spk = (mem > 1.0f) ? 1.0f : 0.0f;
    facc += spk;

    if ((tid & 3) == 0) ksh[39 + (tid >> 2)] = spk;   // publish spike

    const u64 bal = __ballot(spk != 0.0f);
    if (bal && (tid & 63) == 0) atomicOr(&sflag[st % 3], 1u);

    if (xload && tid < 39) ksh[tid] = xv;

    if (m10 == 9) {
      if ((tid & 3) == 0) frow[(st / 10) * HID] = facc * 0.1f;
      facc = 0.f;
    }
    __syncthreads();                     // k + flag ready for next step
    F = sflag[st % 3];
  }
}

// ------------------------------------------------------------- readout ----
__global__ void ro_matmul(const float* __restrict__ FRAMES,
                          const float* __restrict__ w_ro,
                          const float* __restrict__ b_ro,
                          float* __restrict__ Y)
{
  const int bid = blockIdx.x;          // s*32 + b
  const int s = bid >> 5, b = bid & 31;
  __shared__ float row[512];
  const float* Ff = FRAMES + ((size_t)(0 * 32 + b) * SFRAMES + s) * HID;
  const float* Fb = FRAMES + ((size_t)(1 * 32 + b) * SFRAMES + (SFRAMES - 1 - s)) * HID;
  for (int i = threadIdx.x; i < HID; i += 64) {
    row[i] = Ff[i];
    row[HID + i] = Fb[i];
  }
  __syncthreads();
  const int o = threadIdx.x;
  if (o < OUTC) {
    float acc = b_ro[o];
    const float* wr = w_ro + (size_t)o * 512;
#pragma unroll 8
    for (int k = 0; k < 512; ++k) acc += row[k] * wr[k];
    Y[(size_t)bid * OUTC + o] = acc;
  }
}

__global__ void ro_scan(const float* __restrict__ Y,
                        const float* __restrict__ tau_ro,
                        const int* __restrict__ labels,
                        float* __restrict__ out)
{
  const int b = blockIdx.x;            // 32 blocks
  const int o = threadIdx.x;           // 64 threads
  __shared__ float mems[SFRAMES * 40];
  if (o < OUTC) {
    const float ar = 1.0f / (1.0f + expf(-tau_ro[o]));
    const float om = 1.0f - ar;
    float m = 0.0f;
    for (int s = 0; s < SFRAMES; ++s) {
      m = ar * m + om * Y[((size_t)s * 32 + b) * OUTC + o];
      mems[s * 40 + o] = m;
    }
  }
  __syncthreads();
  for (int s = threadIdx.x; s < SFRAMES; s += 64) {
    float mx = -1e30f;
    for (int j = 0; j < OUTC; ++j) mx = fmaxf(mx, mems[s * 40 + j]);
    float se = 0.0f;
    for (int j = 0; j < OUTC; ++j) se += expf(mems[s * 40 + j] - mx);
    const float lse = logf(se);
    float* op = out + ((size_t)s * 32 + b) * OUTC;
    for (int j = 0; j < OUTC; ++j) op[j] = mems[s * 40 + j] - mx - lse;
    const int lab = labels[b * SFRAMES + s];
    const float nll = -(mems[s * 40 + lab] - mx - lse);
    atomicAdd(out + SFRAMES * 32 * OUTC, nll * (1.0f / 32.0f));
  }
}

// -------------------------------------------------------------- launch ----
extern "C" void kernel_launch(void* const* d_in, const int* in_sizes, int n_in,
                              void* d_out, int out_size, void* d_ws, size_t ws_size,
                              hipStream_t stream)
{
  const float* x        = (const float*)d_in[0];
  const int*   labels   = (const int*)d_in[1];
  const float* w_fw     = (const float*)d_in[2];
  const float* b_fw     = (const float*)d_in[3];
  const float* tau_m_fw = (const float*)d_in[4];
  const float* tau_n_fw = (const float*)d_in[5];
  const float* mask_fw  = (const float*)d_in[6];
  const float* w_bw     = (const float*)d_in[7];
  const float* b_bw     = (const float*)d_in[8];
  const float* tau_m_bw = (const float*)d_in[9];
  const float* tau_n_bw = (const float*)d_in[10];
  const float* mask_bw  = (const float*)d_in[11];
  const float* w_ro     = (const float*)d_in[12];
  const float* b_ro     = (const float*)d_in[13];
  const float* tau_m_ro = (const float*)d_in[14];
  float* out = (float*)d_out;

  char* ws = (char*)d_ws;
  float* W      = (float*)(ws + WS_W);
  u16*   OFF    = (u16*)(ws + WS_OFF);
  float* BETA   = (float*)(ws + WS_BETA);
  float* CB     = (float*)(ws + WS_CB);
  float* ALPHA  = (float*)(ws + WS_ALPHA);
  float* FRAMES = (float*)(ws + WS_FRAMES);
  float* Y      = (float*)(ws + WS_Y);

  hipMemsetAsync(out + SFRAMES * 32 * OUTC, 0, sizeof(float), stream);

  build_sparse<<<16, 256, 0, stream>>>(w_fw, b_fw, tau_n_fw, mask_fw,
                                       w_bw, b_bw, tau_n_bw, mask_bw,
                                       tau_m_fw, tau_m_bw,
                                       W, OFF, BETA, CB, ALPHA);
  snn_recurrent<<<64, 1024, 0, stream>>>(x, W, OFF, BETA, CB, ALPHA, FRAMES);
  ro_matmul<<<SFRAMES * 32, 64, 0, stream>>>(FRAMES, w_ro, b_ro, Y);
  ro_scan<<<32, 64, 0, stream>>>(Y, tau_m_ro, labels, out);
}

// Round 5
// 983.510 us; speedup vs baseline: 24.0415x; 2.4916x over previous
//
#include <hip/hip_runtime.h>
#include <math.h>

typedef unsigned short u16;
typedef unsigned int u32;
typedef unsigned long long u64;

#define NSYN 37
#define NB   2048
#define KS   296
#define NIN  39
#define TSTEPS 2000
#define SFRAMES 200
#define HID 256
#define OUTC 39

// ws layout (byte offsets, 16B aligned)
#define WS_WIT    0u          // float [2][39][2048] dense input weights (transposed)
#define WS_WSPK   638976u     // float [2][37][2048] spike-synapse weights
#define WS_OFFSPK 1245184u    // u16   [2][37][2048] spike LDS byte offsets
#define WS_CBIAS  1548288u    // float [2][2048]     raw bias
#define WS_BETA   1564672u    // float [2][2048]
#define WS_ALPHA  1581056u    // float [2][256]
#define WS_FRAMES 1583104u    // float [2][32][200][256]
#define WS_Y      14690304u   // float [200][32][39]
#define WS_LIN    15688704u   // float [2][32][200][2048]  (optional, 100 MB)
#define WS_NEED_FULL (15688704ull + 104857600ull)

// ---------------------------------------------------------------- setup ----
__global__ void build_tables(
    const float* __restrict__ w_fw, const float* __restrict__ b_fw,
    const float* __restrict__ tau_n_fw, const float* __restrict__ mask_fw,
    const float* __restrict__ w_bw, const float* __restrict__ b_bw,
    const float* __restrict__ tau_n_bw, const float* __restrict__ mask_bw,
    const float* __restrict__ tau_m_fw, const float* __restrict__ tau_m_bw,
    float* __restrict__ WiT, float* __restrict__ Wspk, u16* __restrict__ OFFspk,
    float* __restrict__ CBIAS, float* __restrict__ BETA, float* __restrict__ ALPHA)
{
  const int rid = blockIdx.x * 256 + threadIdx.x;
  if (rid < 2 * NB) {
    const int dir = rid >> 11, r = rid & (NB - 1);
    const float* w  = dir ? w_bw : w_fw;
    const float* mk = dir ? mask_bw : mask_fw;
    const float* bb = dir ? b_bw : b_fw;
    const float* tn = dir ? tau_n_bw : tau_n_fw;
    float* wit = WiT + (size_t)dir * (NIN * NB);
    for (int c = 0; c < NIN; ++c) wit[c * NB + r] = 0.0f;
    int sc = 0;
    for (int j = 0; j < KS; ++j) {
      const float m = mk[(size_t)r * KS + j];
      if (m != 0.0f) {
        const float wv = w[(size_t)r * KS + j];
        if (j < NIN) {
          wit[j * NB + r] = wv;
        } else {
          // j==295 (pad column) maps to byte offset 256*4 -> permanent-zero slot
          Wspk[(size_t)dir * (NSYN * NB) + (size_t)sc * NB + r]   = wv;
          OFFspk[(size_t)dir * (NSYN * NB) + (size_t)sc * NB + r] = (u16)((j - NIN) * 4);
          ++sc;
        }
      }
    }
    for (; sc < NSYN; ++sc) {
      Wspk[(size_t)dir * (NSYN * NB) + (size_t)sc * NB + r]   = 0.0f;
      OFFspk[(size_t)dir * (NSYN * NB) + (size_t)sc * NB + r] = (u16)(256 * 4);
    }
    BETA[dir * NB + r]  = 1.0f / (1.0f + expf(-tn[r]));
    CBIAS[dir * NB + r] = bb[r];
  }
  if (rid < 2 * HID) {
    const int dir = rid >> 8, h = rid & (HID - 1);
    const float* tm = dir ? tau_m_bw : tau_m_fw;
    ALPHA[rid] = 1.0f / (1.0f + expf(-tm[h]));
  }
}

// --------------------------------------------- per-frame input gather ----
// lin_in[dir][b][frame][branch] = bias[branch] + sum_c Wi[branch][c]*x[b][frame][c]
// grid = 2*SFRAMES blocks (dir,frame), 256 threads, thread t owns branches 8t..8t+7
__global__ __launch_bounds__(256) void lin_precompute(
    const float* __restrict__ x, const float* __restrict__ WiT,
    const float* __restrict__ CBIAS, float* __restrict__ LIN)
{
  const int dir = blockIdx.x / SFRAMES;
  const int fr  = blockIdx.x % SFRAMES;
  const int t = threadIdx.x;
  const int r0 = t * 8;
  __shared__ float xs[32 * NIN];
  for (int i = t; i < 32 * NIN; i += 256) {
    const int b = i / NIN, c = i - b * NIN;
    xs[i] = x[(size_t)b * (SFRAMES * NIN) + fr * NIN + c];
  }
  __syncthreads();
  const float* wit = WiT + (size_t)dir * (NIN * NB) + r0;
  float bias[8];
  *reinterpret_cast<float4*>(&bias[0]) = *reinterpret_cast<const float4*>(CBIAS + dir * NB + r0);
  *reinterpret_cast<float4*>(&bias[4]) = *reinterpret_cast<const float4*>(CBIAS + dir * NB + r0 + 4);
#pragma unroll 1
  for (int bt = 0; bt < 8; ++bt) {
    float acc[4][8];
#pragma unroll
    for (int q = 0; q < 4; ++q)
#pragma unroll
      for (int k = 0; k < 8; ++k) acc[q][k] = 0.0f;
#pragma unroll 1
    for (int c = 0; c < NIN; ++c) {
      float wv[8];
      *reinterpret_cast<float4*>(&wv[0]) = *reinterpret_cast<const float4*>(wit + c * NB);
      *reinterpret_cast<float4*>(&wv[4]) = *reinterpret_cast<const float4*>(wit + c * NB + 4);
#pragma unroll
      for (int q = 0; q < 4; ++q) {
        const float sx = xs[(bt * 4 + q) * NIN + c];
#pragma unroll
        for (int k = 0; k < 8; ++k) acc[q][k] += wv[k] * sx;
      }
    }
#pragma unroll
    for (int q = 0; q < 4; ++q) {
      const int b = bt * 4 + q;
      float* dst = LIN + (((size_t)(dir * 32 + b) * SFRAMES) + fr) * NB + r0;
      float o[8];
#pragma unroll
      for (int k = 0; k < 8; ++k) o[k] = acc[q][k] + bias[k];
      *reinterpret_cast<float4*>(&dst[0]) = *reinterpret_cast<const float4*>(&o[0]);
      *reinterpret_cast<float4*>(&dst[4]) = *reinterpret_cast<const float4*>(&o[4]);
    }
  }
}

// ------------------------------------------------------- recurrent core ----
template<bool HAVELIN>
__device__ __forceinline__ void load_lin(float* dst, int fr,
    const float* linb, const float* xg, const float* wit, const float* bias)
{
  if constexpr (HAVELIN) {
    const float4 a = *reinterpret_cast<const float4*>(linb + (size_t)fr * NB);
    const float4 c = *reinterpret_cast<const float4*>(linb + (size_t)fr * NB + 4);
    dst[0] = a.x; dst[1] = a.y; dst[2] = a.z; dst[3] = a.w;
    dst[4] = c.x; dst[5] = c.y; dst[6] = c.z; dst[7] = c.w;
  } else {
    float a[8];
#pragma unroll
    for (int j = 0; j < 8; ++j) a[j] = bias[j];
#pragma unroll 1
    for (int c = 0; c < NIN; ++c) {
      const float sx = xg[fr * NIN + c];
      const float4 w0 = *reinterpret_cast<const float4*>(wit + c * NB);
      const float4 w1 = *reinterpret_cast<const float4*>(wit + c * NB + 4);
      a[0] += w0.x * sx; a[1] += w0.y * sx; a[2] += w0.z * sx; a[3] += w0.w * sx;
      a[4] += w1.x * sx; a[5] += w1.y * sx; a[6] += w1.z * sx; a[7] += w1.w * sx;
    }
#pragma unroll
    for (int j = 0; j < 8; ++j) dst[j] = a[j];
  }
}

// grid = 64 (dir*32 + batch), block = 256, thread t owns neuron t (branches 8t..8t+7)
template<bool HAVELIN>
__global__ __launch_bounds__(256) void snn_scan(
    const float* __restrict__ x, const float* __restrict__ LIN,
    const float* __restrict__ WiT, const float* __restrict__ Wspk,
    const u16* __restrict__ OFFspk, const float* __restrict__ CBIAS,
    const float* __restrict__ BETA, const float* __restrict__ ALPHA,
    float* __restrict__ FRAMES)
{
  const int wg  = blockIdx.x;
  const int dir = wg >> 5, b = wg & 31;
  const int t   = threadIdx.x;
  const int r0  = t * 8;

  __shared__ float spkbuf[2][260];   // double-buffered spikes + zero slot @256
  __shared__ u32 sflag[3];
  spkbuf[0][t] = 0.0f; spkbuf[1][t] = 0.0f;
  if (t < 4) { spkbuf[0][256 + t] = 0.0f; spkbuf[1][256 + t] = 0.0f; }
  if (t < 3) sflag[t] = 0u;

  float be[8];
  *reinterpret_cast<float4*>(&be[0]) = *reinterpret_cast<const float4*>(BETA + dir * NB + r0);
  *reinterpret_cast<float4*>(&be[4]) = *reinterpret_cast<const float4*>(BETA + dir * NB + r0 + 4);
  const float alpha = ALPHA[dir * HID + t];
  const float oma   = 1.0f - alpha;

  const float* linb = HAVELIN ? (LIN + ((size_t)(dir * 32 + b) * SFRAMES) * NB + r0) : nullptr;
  const float* xg   = x + (size_t)b * (SFRAMES * NIN);
  const float* wit  = WiT + (size_t)dir * (NIN * NB) + r0;
  float bias[8];
  if constexpr (!HAVELIN) {
    *reinterpret_cast<float4*>(&bias[0]) = *reinterpret_cast<const float4*>(CBIAS + dir * NB + r0);
    *reinterpret_cast<float4*>(&bias[4]) = *reinterpret_cast<const float4*>(CBIAS + dir * NB + r0 + 4);
  }
  const float* wsp = Wspk + (size_t)dir * (NSYN * NB);
  const u16*   ofp = OFFspk + (size_t)dir * (NSYN * NB);

  float lin[8], nlin[8], pl[8], d[8];
#pragma unroll
  for (int j = 0; j < 8; ++j) d[j] = 0.0f;
  float mem = 0.0f, spk = 0.0f, facc = 0.0f;
  u32 F = 0;

  load_lin<HAVELIN>(lin, 0, linb, xg, wit, bias);
  if (dir == 1) load_lin<HAVELIN>(nlin, 199, linb, xg, wit, bias);
  else {
#pragma unroll
    for (int j = 0; j < 8; ++j) nlin[j] = 0.0f;
  }
#pragma unroll
  for (int j = 0; j < 8; ++j) pl[j] = (1.0f - be[j]) * lin[j];

  float* frow = FRAMES + ((size_t)(dir * 32 + b) * SFRAMES) * HID + t;
  __syncthreads();

#pragma unroll 1
  for (int st = 0; st < TSTEPS; ++st) {
    const int m10 = st - (st / 10) * 10;
    // commit prefetched frame: fw frames change at st%10==0, bw at st%10==1
    const bool commit = (dir == 0) ? (m10 == 0 && st > 0) : (m10 == 1);
    if (commit) {
#pragma unroll
      for (int j = 0; j < 8; ++j) { lin[j] = nlin[j]; pl[j] = (1.0f - be[j]) * lin[j]; }
    }

    if (F) {   // spikes live last step: exact gather of spike contributions
      const char* kb = reinterpret_cast<const char*>(&spkbuf[(st + 1) & 1][0]);
      float acc[8];
#pragma unroll
      for (int j = 0; j < 8; ++j) acc[j] = lin[j];
#pragma unroll 1
      for (int s = 0; s < NSYN; ++s) {
        float wv[8];
        *reinterpret_cast<float4*>(&wv[0]) = *reinterpret_cast<const float4*>(wsp + (size_t)s * NB + r0);
        *reinterpret_cast<float4*>(&wv[4]) = *reinterpret_cast<const float4*>(wsp + (size_t)s * NB + r0 + 4);
        const uint4 ov = *reinterpret_cast<const uint4*>(ofp + (size_t)s * NB + r0);
        const u16* of = reinterpret_cast<const u16*>(&ov);
#pragma unroll
        for (int j = 0; j < 8; ++j)
          acc[j] += wv[j] * *reinterpret_cast<const float*>(kb + of[j]);
      }
#pragma unroll
      for (int j = 0; j < 8; ++j) d[j] = be[j] * d[j] + (1.0f - be[j]) * acc[j];
    } else {   // silent: cached (1-beta)*lin, bitwise-equal to zero-spike gather
#pragma unroll
      for (int j = 0; j < 8; ++j) d[j] = be[j] * d[j] + pl[j];
    }

    const float s01 = d[0] + d[1], s23 = d[2] + d[3];
    const float s45 = d[4] + d[5], s67 = d[6] + d[7];
    const float dsum = (s01 + s23) + (s45 + s67);
    mem = alpha * mem + oma * dsum - spk;
    spk = (mem > 1.0f) ? 1.0f : 0.0f;
    facc += spk;

    spkbuf[st & 1][t] = spk;                     // publish to this step's buffer
    if (t == 0) sflag[(st + 1) % 3] = 0u;        // reset 2 epochs ahead of reads
    const u64 bal = __ballot(spk != 0.0f);
    if (bal && (t & 63) == 0) atomicOr(&sflag[st % 3], 1u);

    // prefetch next frame's lin 9 steps early (hides HBM latency)
    const bool pref = (dir == 0) ? (m10 == 1 && st < 1991) : (m10 == 2 && st < 1992);
    if (pref) {
      const int nf = (dir == 0) ? (st + 9) / 10 : 199 - (st + 8) / 10;
      load_lin<HAVELIN>(nlin, nf, linb, xg, wit, bias);
    }

    if (m10 == 9) { frow[(st / 10) * HID] = facc * 0.1f; facc = 0.0f; }
    __syncthreads();
    F = sflag[st % 3];
  }
}

// ------------------------------------------------------------- readout ----
__global__ void ro_matmul(const float* __restrict__ FRAMES,
                          const float* __restrict__ w_ro,
                          const float* __restrict__ b_ro,
                          float* __restrict__ Y)
{
  const int bid = blockIdx.x;          // s*32 + b
  const int s = bid >> 5, b = bid & 31;
  __shared__ float row[512];
  const float* Ff = FRAMES + ((size_t)(0 * 32 + b) * SFRAMES + s) * HID;
  const float* Fb = FRAMES + ((size_t)(1 * 32 + b) * SFRAMES + (SFRAMES - 1 - s)) * HID;
  for (int i = threadIdx.x; i < HID; i += 64) {
    row[i] = Ff[i];
    row[HID + i] = Fb[i];
  }
  __syncthreads();
  const int o = threadIdx.x;
  if (o < OUTC) {
    float acc = b_ro[o];
    const float* wr = w_ro + (size_t)o * 512;
#pragma unroll 8
    for (int k = 0; k < 512; ++k) acc += row[k] * wr[k];
    Y[(size_t)bid * OUTC + o] = acc;
  }
}

__global__ void ro_scan(const float* __restrict__ Y,
                        const float* __restrict__ tau_ro,
                        const int* __restrict__ labels,
                        float* __restrict__ out)
{
  const int b = blockIdx.x;            // 32 blocks
  const int o = threadIdx.x;           // 64 threads
  __shared__ float mems[SFRAMES * 40];
  if (o < OUTC) {
    const float ar = 1.0f / (1.0f + expf(-tau_ro[o]));
    const float om = 1.0f - ar;
    float m = 0.0f;
    for (int s = 0; s < SFRAMES; ++s) {
      m = ar * m + om * Y[((size_t)s * 32 + b) * OUTC + o];
      mems[s * 40 + o] = m;
    }
  }
  __syncthreads();
  for (int s = threadIdx.x; s < SFRAMES; s += 64) {
    float mx = -1e30f;
    for (int j = 0; j < OUTC; ++j) mx = fmaxf(mx, mems[s * 40 + j]);
    float se = 0.0f;
    for (int j = 0; j < OUTC; ++j) se += expf(mems[s * 40 + j] - mx);
    const float lse = logf(se);
    float* op = out + ((size_t)s * 32 + b) * OUTC;
    for (int j = 0; j < OUTC; ++j) op[j] = mems[s * 40 + j] - mx - lse;
    const int lab = labels[b * SFRAMES + s];
    const float nll = -(mems[s * 40 + lab] - mx - lse);
    atomicAdd(out + SFRAMES * 32 * OUTC, nll * (1.0f / 32.0f));
  }
}

// -------------------------------------------------------------- launch ----
extern "C" void kernel_launch(void* const* d_in, const int* in_sizes, int n_in,
                              void* d_out, int out_size, void* d_ws, size_t ws_size,
                              hipStream_t stream)
{
  const float* x        = (const float*)d_in[0];
  const int*   labels   = (const int*)d_in[1];
  const float* w_fw     = (const float*)d_in[2];
  const float* b_fw     = (const float*)d_in[3];
  const float* tau_m_fw = (const float*)d_in[4];
  const float* tau_n_fw = (const float*)d_in[5];
  const float* mask_fw  = (const float*)d_in[6];
  const float* w_bw     = (const float*)d_in[7];
  const float* b_bw     = (const float*)d_in[8];
  const float* tau_m_bw = (const float*)d_in[9];
  const float* tau_n_bw = (const float*)d_in[10];
  const float* mask_bw  = (const float*)d_in[11];
  const float* w_ro     = (const float*)d_in[12];
  const float* b_ro     = (const float*)d_in[13];
  const float* tau_m_ro = (const float*)d_in[14];
  float* out = (float*)d_out;

  char* ws = (char*)d_ws;
  float* WiT    = (float*)(ws + WS_WIT);
  float* Wspk   = (float*)(ws + WS_WSPK);
  u16*   OFFspk = (u16*)(ws + WS_OFFSPK);
  float* CBIAS  = (float*)(ws + WS_CBIAS);
  float* BETA   = (float*)(ws + WS_BETA);
  float* ALPHA  = (float*)(ws + WS_ALPHA);
  float* FRAMES = (float*)(ws + WS_FRAMES);
  float* Y      = (float*)(ws + WS_Y);
  float* LIN    = (float*)(ws + WS_LIN);

  const bool haveLin = (ws_size >= WS_NEED_FULL);

  hipMemsetAsync(out + SFRAMES * 32 * OUTC, 0, sizeof(float), stream);

  build_tables<<<16, 256, 0, stream>>>(w_fw, b_fw, tau_n_fw, mask_fw,
                                       w_bw, b_bw, tau_n_bw, mask_bw,
                                       tau_m_fw, tau_m_bw,
                                       WiT, Wspk, OFFspk, CBIAS, BETA, ALPHA);
  if (haveLin) {
    lin_precompute<<<2 * SFRAMES, 256, 0, stream>>>(x, WiT, CBIAS, LIN);
    snn_scan<true><<<64, 256, 0, stream>>>(x, LIN, WiT, Wspk, OFFspk, CBIAS,
                                           BETA, ALPHA, FRAMES);
  } else {
    snn_scan<false><<<64, 256, 0, stream>>>(x, LIN, WiT, Wspk, OFFspk, CBIAS,
                                            BETA, ALPHA, FRAMES);
  }
  ro_matmul<<<SFRAMES * 32, 64, 0, stream>>>(FRAMES, w_ro, b_ro, Y);
  ro_scan<<<32, 64, 0, stream>>>(Y, tau_m_ro, labels, out);
}